// Round 9
// baseline (227.692 us; speedup 1.0000x reference)
//
#include <hip/hip_runtime.h>
#include <hip/hip_bf16.h>
#include <cstdint>
#include <cstddef>

// ---------------------------------------------------------------------------
// LlamaAttention forward: out = Attn(RoPE(x@wq), RoPE(x@wk), x@wv) @ wo
// B=2 T=2048 C=2048 NH=32 NKV=8 D=64, causal, GQA rep=4, scale=1/8.
// R9: GEMM fragment-reuse fix — per-wave output 64x128 (was 64x64).
// LDS-traffic/FLOP halves: ceiling 30% -> 40% MfmaUtil. 128x128 tile,
// 2 waves/block (128 thr), BK=64, 2-phase double buffer, both-sides XOR
// swizzle. RoPE fused in QKV epilogue; V^T via wave-private LDS transpose.
// ---------------------------------------------------------------------------

using bf16 = __hip_bfloat16;
using f32x4  = __attribute__((ext_vector_type(4))) float;
using f32x16 = __attribute__((ext_vector_type(16))) float;
using short8 = __attribute__((ext_vector_type(8))) short;
using u32x4  = __attribute__((ext_vector_type(4))) unsigned int;

typedef __attribute__((address_space(1))) const void* gp1_t;
typedef __attribute__((address_space(3))) void*       lp3_t;

#define GLOAD_LDS16(g, l)                                                     \
  __builtin_amdgcn_global_load_lds((gp1_t)(const void*)(g), (lp3_t)(void*)(l), 16, 0, 0)

#define MFMA32(a, b, c) __builtin_amdgcn_mfma_f32_32x32x16_bf16(a, b, c, 0, 0, 0)

static constexpr int Bd  = 2;
static constexpr int Td  = 2048;
static constexpr int Cd  = 2048;
static constexpr int NH  = 32;
static constexpr int NKV = 8;
static constexpr int HD  = 64;
static constexpr int Md  = Bd * Td;     // 4096 rows

__device__ inline float bf2f(unsigned short u) {
  union { unsigned int i; float f; } v; v.i = ((unsigned int)u) << 16; return v.f;
}
__device__ inline unsigned short f2bfbits(float f) {
  union { float f; unsigned int u; } v; v.f = f;
  unsigned int r = v.u + 0x7fffu + ((v.u >> 16) & 1u);   // RNE
  return (unsigned short)(r >> 16);
}
__device__ inline unsigned int pkbf(float a, float b) {   // lo=bf16(a), hi=bf16(b)
  unsigned int r;
  asm("v_cvt_pk_bf16_f32 %0, %1, %2" : "=v"(r) : "v"(a), "v"(b));
  return r;
}
// v_permlane32_swap_b32 d, s:  after: d = {d.lo, s.lo}, s = {d.hi, s.hi}.
__device__ inline void plswapf(float& a, float& b) {
  asm("v_permlane32_swap_b32 %0, %1" : "+v"(a), "+v"(b));
}
__device__ inline void plswapu(unsigned int& a, unsigned int& b) {
  asm("v_permlane32_swap_b32 %0, %1" : "+v"(a), "+v"(b));
}
__device__ inline float hmax16(const f32x16& v) {
  float a0 = fmaxf(v[0], v[1]),   a1 = fmaxf(v[2], v[3]);
  float a2 = fmaxf(v[4], v[5]),   a3 = fmaxf(v[6], v[7]);
  float a4 = fmaxf(v[8], v[9]),   a5 = fmaxf(v[10], v[11]);
  float a6 = fmaxf(v[12], v[13]), a7 = fmaxf(v[14], v[15]);
  float b0 = fmaxf(a0, a1), b1 = fmaxf(a2, a3);
  float b2 = fmaxf(a4, a5), b3 = fmaxf(a6, a7);
  return fmaxf(fmaxf(b0, b1), fmaxf(b2, b3));
}
__device__ inline float hsum16(const f32x16& v) {
  float a0 = v[0]+v[1],   a1 = v[2]+v[3],   a2 = v[4]+v[5],   a3 = v[6]+v[7];
  float a4 = v[8]+v[9],   a5 = v[10]+v[11], a6 = v[12]+v[13], a7 = v[14]+v[15];
  float b0 = a0+a1, b1 = a2+a3, b2 = a4+a5, b3 = a6+a7;
  return (b0+b1)+(b2+b3);
}

// ---------------- prep1: x->bf16 + wq/wk/wv fp32->bf16^T -------------------
__global__ __launch_bounds__(256) void prep1_kernel(const float* __restrict__ x,
                                                    const float* __restrict__ wq,
                                                    const float* __restrict__ wk,
                                                    const float* __restrict__ wv,
                                                    bf16* __restrict__ xb,
                                                    bf16* __restrict__ w1) {
  __shared__ float tile[32][33];
  int bid = blockIdx.x, tid = threadIdx.x;
  if (bid < 8192) {
    int i = bid * 256 + tid;
    float4 v = ((const float4*)x)[i];
    ushort4 o;
    o.x = f2bfbits(v.x); o.y = f2bfbits(v.y); o.z = f2bfbits(v.z); o.w = f2bfbits(v.w);
    ((ushort4*)xb)[i] = o;
    return;
  }
  const float* in; bf16* out; int Cc, bx, by;
  if (bid < 12288)      { int l = bid - 8192;  in = wq; out = w1;                        Cc = 2048; bx = l & 63; by = l >> 6; }
  else if (bid < 13312) { int l = bid - 12288; in = wk; out = w1 + (size_t)2048 * 2048;  Cc = 512;  bx = l & 15; by = l >> 4; }
  else                  { int l = bid - 13312; in = wv; out = w1 + (size_t)2560 * 2048;  Cc = 512;  bx = l & 15; by = l >> 4; }
  int tx = tid & 31, ty = tid >> 5;
  int col = bx * 32 + tx;
#pragma unroll
  for (int i = 0; i < 4; ++i) {
    int row = by * 32 + ty + i * 8;
    tile[ty + i * 8][tx] = in[(size_t)row * Cc + col];
  }
  __syncthreads();
#pragma unroll
  for (int i = 0; i < 4; ++i) {
    int orow = bx * 32 + ty + i * 8;
    int ocol = by * 32 + tx;
    out[(size_t)orow * 2048 + ocol] = __float2bfloat16(tile[tx][ty + i * 8]);
  }
}

// ---------------- fp32 [R][Cc] -> bf16 transpose [Cc][R] (wo) --------------
__global__ __launch_bounds__(256) void transpose_f2b(const float* __restrict__ in,
                                                     bf16* __restrict__ out,
                                                     int R, int Cc) {
  __shared__ float tile[32][33];
  int tx = threadIdx.x & 31, ty = threadIdx.x >> 5;
  int bx = blockIdx.x, by = blockIdx.y;
  int col = bx * 32 + tx;
#pragma unroll
  for (int i = 0; i < 4; ++i) {
    int row = by * 32 + ty + i * 8;
    tile[ty + i * 8][tx] = in[(size_t)row * Cc + col];
  }
  __syncthreads();
#pragma unroll
  for (int i = 0; i < 4; ++i) {
    int orow = bx * 32 + ty + i * 8;
    int ocol = by * 32 + tx;
    out[(size_t)orow * R + ocol] = __float2bfloat16(tile[tx][ty + i * 8]);
  }
}

// ---------------- GEMM: C[M][N] = A[M][K] * Bt[N][K]^T ---------------------
// 128x128 tile, 2 waves (128 thr); wave w owns rows [w*64,w*64+64) x all 128
// cols -> acc[4][8] (128 VGPR). BK=64, 2-phase double buffer, both-sides
// XOR swizzle (conflict-free ds_read_b128). Natural 2D grid.
// MODE 2: fp32 row-major [M][N].
// MODE 3: fused QKV epilogue — RoPE in-register for Q (prescaled) and K;
//         V^T via wave-private LDS transpose (16KB slab).
template <int MODE>
__global__ __launch_bounds__(128, 2) void gemm_bf16(const bf16* __restrict__ A,
                                                    const bf16* __restrict__ Bt,
                                                    void* __restrict__ Cp,
                                                    int M, int N, int K) {
  __shared__ __align__(16) bf16 Al[2][128 * 64];   // 2 x 16 KB
  __shared__ __align__(16) bf16 Bl[2][128 * 64];   // 2 x 16 KB
  int tid = threadIdx.x;
  int w = tid >> 6, lane = tid & 63;
  int lr = lane & 15, lg = lane >> 4;
  int m0 = blockIdx.x * 128, n0 = blockIdx.y * 128;
  f32x4 acc[4][8] = {};

  size_t Kb = (size_t)K * 2;
  int c8 = lane & 7, r8 = lane >> 3;           // src chunk, row-in-octet (0..7)
  // wave w stages A rows [w*64 + j*8 + r8) and B rows [w*64 + j*8 + r8)
  const char* Asrc = (const char*)A + (size_t)(m0 + w * 64 + r8) * Kb + ((c8 ^ r8) << 4);
  const char* Bsrc = (const char*)Bt + (size_t)(n0 + w * 64 + r8) * Kb + ((c8 ^ r8) << 4);

#define GSTAGE(kt, bb) do {                                                   \
    char* ald = (char*)&Al[bb][0] + w * 8192;                                 \
    char* bld = (char*)&Bl[bb][0] + w * 8192;                                 \
    _Pragma("unroll")                                                         \
    for (int j = 0; j < 8; ++j) {                                             \
      GLOAD_LDS16(Asrc + (size_t)j * 8 * Kb + (size_t)(kt) * 2, ald + j * 1024); \
      GLOAD_LDS16(Bsrc + (size_t)j * 8 * Kb + (size_t)(kt) * 2, bld + j * 1024); \
    }                                                                         \
  } while (0)

  int nkt = K >> 6;
  GSTAGE(0, 0);
  __syncthreads();

  for (int t = 0; t < nkt; ++t) {
    int cur = t & 1;
    if (t + 1 < nkt) GSTAGE((t + 1) << 6, cur ^ 1);   // issue next-tile loads first
    const char* Ab = (const char*)&Al[cur][0];
    const char* Bb = (const char*)&Bl[cur][0];
#pragma unroll
    for (int kk = 0; kk < 2; ++kk) {
      int cb = (((kk << 2) | lg) ^ (lr & 7)) << 4;
      short8 af[4], bfr[8];
#pragma unroll
      for (int f = 0; f < 4; ++f)
        af[f] = *(const short8*)(Ab + (size_t)(w * 64 + f * 16 + lr) * 128 + cb);
#pragma unroll
      for (int j = 0; j < 8; ++j)
        bfr[j] = *(const short8*)(Bb + (size_t)(j * 16 + lr) * 128 + cb);
#pragma unroll
      for (int i = 0; i < 4; ++i)
#pragma unroll
        for (int j = 0; j < 8; ++j)
          acc[i][j] = __builtin_amdgcn_mfma_f32_16x16x32_bf16(af[i], bfr[j], acc[i][j], 0, 0, 0);
    }
    __syncthreads();   // drains next-tile loads + protects buffers
  }
#undef GSTAGE

  bf16* Qb  = (bf16*)Cp;
  bf16* Kb2 = Qb + (size_t)Bd * NH * Td * HD;
  bf16* Vtb = Kb2 + (size_t)Bd * NKV * Td * HD;

  if (MODE == 3 && n0 >= 2560) {
    // ---- V^T epilogue: wave-private 16KB LDS transpose, coalesced stores --
    // wave w: t rows [m0+w*64, +64), d cols 0..127 (2 heads).
    int b  = m0 >> 11;
    int tg = (m0 & 2047) + w * 64;
    int h0 = (n0 - 2560) >> 6;
    char* tb = (char*)&Al[0][0] + w * 16384;   // slab [128 d][64 t'] bf16
#pragma unroll
    for (int i = 0; i < 4; ++i)
#pragma unroll
      for (int j = 0; j < 8; ++j)
#pragma unroll
        for (int r = 0; r < 4; r += 2) {
          int d  = j * 16 + lr;                // 0..127
          int tt = i * 16 + lg * 4 + r;
          unsigned int pk = pkbf(acc[i][j][r], acc[i][j][r + 1]);
          *(unsigned int*)(tb + (((size_t)d * 128 + tt * 2) ^ ((d & 7) << 4))) = pk;
        }
    asm volatile("s_waitcnt lgkmcnt(0)" ::: "memory");
    __builtin_amdgcn_sched_barrier(0);
    char* Vdst = (char*)Vtb + ((((size_t)b * NKV + h0) * 64) * Td + tg) * 2;
#pragma unroll
    for (int p = 0; p < 16; ++p) {
      int d  = p * 8 + (lane >> 3);            // 0..127
      int tc = lane & 7;
      u32x4 v = *(const u32x4*)(tb + (((size_t)d * 128 + tc * 16) ^ ((d & 7) << 4)));
      int hh = d >> 6, dd = d & 63;
      *(u32x4*)(Vdst + ((size_t)hh * 64 + dd) * Td * 2 + tc * 16) = v;
    }
    return;
  }

  if (MODE == 3) {
    // ---- Q/K epilogue with fused RoPE ----
    const float RC = -0.41524101186092029f;        // -log2(10000)/32
    float sc = (n0 < 2048) ? 0.18033688011112042f : 1.0f;   // Q: 0.125*log2e
    int odd = lane & 1;
#pragma unroll
    for (int j = 0; j < 8; ++j) {
      int ncol = n0 + j * 16 + lr;
      int d  = ncol & 63;
      float inv = __builtin_amdgcn_exp2f((float)(d >> 1) * RC);
#pragma unroll
      for (int i = 0; i < 4; ++i) {
#pragma unroll
        for (int r = 0; r < 4; ++r) {
          int mrow = m0 + w * 64 + i * 16 + lg * 4 + r;
          int t = mrow & 2047;
          float v = acc[i][j][r];
          float p = __shfl_xor(v, 1);
          float rev = (float)t * inv * 0.15915494309189535f;
          rev = rev - floorf(rev);
          float s = __builtin_amdgcn_sinf(rev);
          float c = __builtin_amdgcn_cosf(rev);
          float res = odd ? (v * c + p * s) : (v * c - p * s);
          res *= sc;
          int b = mrow >> 11;
          if (n0 < 2048) {
            int h = ncol >> 6;
            Qb[(((size_t)b * NH + h) * Td + t) * HD + d] = __float2bfloat16(res);
          } else {
            int h = (ncol - 2048) >> 6;
            Kb2[(((size_t)b * NKV + h) * Td + t) * HD + d] = __float2bfloat16(res);
          }
        }
      }
    }
    return;
  }

#pragma unroll
  for (int i = 0; i < 4; ++i)
#pragma unroll
    for (int j = 0; j < 8; ++j)
#pragma unroll
      for (int r = 0; r < 4; ++r) {
        int mrow = m0 + w * 64 + i * 16 + lg * 4 + r;
        int ncol = n0 + j * 16 + lr;
        ((float*)Cp)[(size_t)mrow * N + ncol] = acc[i][j][r];
      }
}

// ---------------- Flash attention (causal, GQA), LDS-staged KV -------------
// grid (B*NH=64, 8 qb), 512 thr = 8 waves; wave w owns q rows qb*256+w*32..+31.
// LPT: qb = 7 - blockIdx.y (heavy blocks first).
// Per kv tile (64x64): wave w stages K rows [w*8,w*8+8) and Vt rows [w*8,+8)
// via ONE global_load_lds dwordx4 each (coalesced), inverse-XOR-swizzled src.
// 2-phase double buffer: STAGE(next) -> compute(cur) -> vmcnt(0)+barrier.
// Softmax: swapped QK^T (S^T col=q=lane&31), in-register, T12 pack, T13 defer.
__global__ __launch_bounds__(512, 4) void attn_kernel(const bf16* __restrict__ Q,
                                                      const bf16* __restrict__ K,
                                                      const bf16* __restrict__ Vt,
                                                      bf16* __restrict__ Y) {
  __shared__ __align__(16) char lds[2 * 16384];   // [buf][K 8KB | V 8KB]
  int tid = threadIdx.x, w = tid >> 6, lane = tid & 63;
  int lq = lane & 31;          // q column (and kv/d row within subtile)
  int H  = lane >> 5;          // lane half
  int qb = 7 - (int)blockIdx.y;
  int bh = blockIdx.x;
  int b = bh >> 5, h = bh & 31, kvh = h >> 2;
  int q0w = qb * 256 + w * 32;
  int qg  = q0w + lq;
  int tmax = qb * 4 + (w >> 1);    // this wave's last compute tile
  int Nt   = qb * 4 + 4;           // tiles staged by the block

  const bf16* Qp = Q + (((size_t)b * NH + h) * Td) * HD;
  const char* Kg = (const char*)(K + (((size_t)b * NKV + kvh) * Td) * HD);   // rows 128B
  const char* Vg = (const char*)(Vt + (((size_t)b * NKV + kvh) * HD) * Td);  // rows 4096B

  // Q B-fragments (pre-scaled in QKV epilogue): qf[ck][j] = Q[qg][ck*16+H*8+j]
  short8 qf[4];
#pragma unroll
  for (int ck = 0; ck < 4; ++ck)
    qf[ck] = *(const short8*)(Qp + (size_t)qg * HD + ck * 16 + H * 8);

  // staging geometry: wave w stages tile rows [w*8, w*8+8), 16B per lane
  int srow   = lane >> 3;                       // 0..7 within the 8-row slab
  int scol16 = ((lane & 7) ^ srow) << 4;        // inverse-swizzled byte col
  const char* Ksrc0 = Kg + (size_t)(w * 8 + srow) * 128 + scol16;
  const char* Vsrc0 = Vg + (size_t)(w * 8 + srow) * 4096 + scol16;
  char* KldsW[2] = { lds + w * 1024,          lds + 16384 + w * 1024 };
  char* VldsW[2] = { lds + 8192 + w * 1024,   lds + 24576 + w * 1024 };

#define STAGE_KV(tt, bb) do {                                                 \
    GLOAD_LDS16(Ksrc0 + (size_t)(tt) * 64 * 128, KldsW[bb]);                  \
    GLOAD_LDS16(Vsrc0 + (size_t)(tt) * 128,      VldsW[bb]);                  \
  } while (0)

  f32x16 acc0 = {}, acc1 = {};     // O^T[d][q], d 0..31 / 32..63
  float m = -3e38f, l = 0.0f;
  int swz = (lq & 7) << 4;
  int rb0 = lq * 128, rb1 = (32 + lq) * 128;

  STAGE_KV(0, 0);
  asm volatile("s_waitcnt vmcnt(0)" ::: "memory");
  __syncthreads();

  for (int t = 0; t < Nt; ++t) {
    int cur = t & 1;
    if (t + 1 < Nt) STAGE_KV(t + 1, cur ^ 1);
    if (t <= tmax) {
      const char* Kl = lds + cur * 16384;
      const char* Vl = Kl + 8192;
      // ---- S^T = K . Q^T ----
      f32x16 s0 = {}, s1 = {};
      __builtin_amdgcn_s_setprio(1);
#pragma unroll
      for (int ck = 0; ck < 4; ++ck) {
        int c = (H * 16 + ck * 32) ^ swz;
        short8 kf0 = *(const short8*)(Kl + rb0 + c);
        short8 kf1 = *(const short8*)(Kl + rb1 + c);
        s0 = MFMA32(kf0, qf[ck], s0);
        s1 = MFMA32(kf1, qf[ck], s1);
      }
      __builtin_amdgcn_s_setprio(0);
      // ---- causal mask (diagonal tile only) ----
      if (t == tmax) {
        int kvb = t * 64;
#pragma unroll
        for (int rr = 0; rr < 16; ++rr) {
          int krel = (rr & 3) + 8 * (rr >> 2) + 4 * H;
          if (kvb + krel > qg)      s0[rr] = -3e38f;
          if (kvb + 32 + krel > qg) s1[rr] = -3e38f;
        }
      }
      // ---- row max (register tree + cross-half permlane swap) ----
      float mx = fmaxf(hmax16(s0), hmax16(s1));
      {
        float mb = mx;
        asm("" : "+v"(mb));
        plswapf(mx, mb);
        mx = fmaxf(mx, mb);
      }
      // ---- defer-rescale (T13, THR=8 in log2 domain) ----
      if (__any(mx > m + 8.0f)) {
        float mn = fmaxf(m, mx);
        float al = __builtin_amdgcn_exp2f(m - mn);
        m = mn;
        l *= al;
#pragma unroll
        for (int rr = 0; rr < 16; ++rr) { acc0[rr] *= al; acc1[rr] *= al; }
      }
      // ---- p = exp2(s - m) ----
#pragma unroll
      for (int rr = 0; rr < 16; ++rr) {
        s0[rr] = __builtin_amdgcn_exp2f(s0[rr] - m);
        s1[rr] = __builtin_amdgcn_exp2f(s1[rr] - m);
      }
      float ps = hsum16(s0) + hsum16(s1);
      {
        float pb = ps;
        asm("" : "+v"(pb));
        plswapf(ps, pb);
        ps += pb;
      }
      l += ps;
      // ---- pack P -> bf16 B-fragments (T12: cvt_pk + permlane32_swap) ----
      short8 pf[4];
#pragma unroll
      for (int tt = 0; tt < 2; ++tt) {
        const f32x16& sv = tt ? s1 : s0;
#pragma unroll
        for (int a2 = 0; a2 < 2; ++a2) {
          unsigned int A0 = pkbf(sv[8*a2 + 0], sv[8*a2 + 1]);
          unsigned int A1 = pkbf(sv[8*a2 + 2], sv[8*a2 + 3]);
          unsigned int B0 = pkbf(sv[8*a2 + 4], sv[8*a2 + 5]);
          unsigned int B1 = pkbf(sv[8*a2 + 6], sv[8*a2 + 7]);
          plswapu(A0, B0);
          plswapu(A1, B1);
          u32x4 t4;
          t4[0] = A0; t4[1] = A1; t4[2] = B0; t4[3] = B1;
          pf[2*tt + a2] = __builtin_bit_cast(short8, t4);
        }
      }
      // ---- O^T += V^T . P ----
      __builtin_amdgcn_s_setprio(1);
#pragma unroll
      for (int ks = 0; ks < 4; ++ks) {
        int c = (H * 16 + ks * 32) ^ swz;
        short8 vf0 = *(const short8*)(Vl + rb0 + c);
        short8 vf1 = *(const short8*)(Vl + rb1 + c);
        acc0 = MFMA32(vf0, pf[ks], acc0);
        acc1 = MFMA32(vf1, pf[ks], acc1);
      }
      __builtin_amdgcn_s_setprio(0);
    }
    asm volatile("s_waitcnt vmcnt(0)" ::: "memory");
    __syncthreads();
  }
#undef STAGE_KV

  // ---- epilogue: normalize, write Y[M][C] ----
  float rn = 1.0f / l;
  bf16* Yp = Y + ((size_t)b * Td + qg) * Cd + h * HD;
#pragma unroll
  for (int rr = 0; rr < 16; rr += 2) {
    int d = (rr & 3) + 8 * (rr >> 2) + 4 * H;   // d, d+1 for rr, rr+1
    unsigned int w0 = pkbf(acc0[rr] * rn, acc0[rr + 1] * rn);
    unsigned int w1 = pkbf(acc1[rr] * rn, acc1[rr + 1] * rn);
    *(unsigned int*)(Yp + d)      = w0;
    *(unsigned int*)(Yp + 32 + d) = w1;
  }
}

// ---------------------------------------------------------------------------
extern "C" void kernel_launch(void* const* d_in, const int* in_sizes, int n_in,
                              void* d_out, int out_size, void* d_ws, size_t ws_size,
                              hipStream_t stream) {
  const float* x  = (const float*)d_in[0];
  const float* wq = (const float*)d_in[1];
  const float* wk = (const float*)d_in[2];
  const float* wv = (const float*)d_in[3];
  const float* wo = (const float*)d_in[4];

  char* ws = (char*)d_ws;
  const size_t o_xb = 0;                                   // 16.78 MB (reused as yb)
  const size_t o_w1 = o_xb + (size_t)Md * Cd * 2;          // 12.58 MB (wqkvT / later woT)
  const size_t o_Q  = o_w1 + (size_t)3072 * Cd * 2;        // 16.78 MB
  const size_t o_K  = o_Q + (size_t)Bd * NH * Td * HD * 2; // 4.19 MB
  const size_t o_V  = o_K + (size_t)Bd * NKV * Td * HD * 2;// 4.19 MB

  bf16* xb  = (bf16*)(ws + o_xb);
  bf16* w1  = (bf16*)(ws + o_w1);
  bf16* Qb  = (bf16*)(ws + o_Q);
  bf16* Kb  = (bf16*)(ws + o_K);
  bf16* Vtb = (bf16*)(ws + o_V);
  bf16* yb  = xb;   // alias: x_bf16 dead after QKV GEMM

  // 1. prep1: x->bf16 + wq/wk/wv transposes (one launch)
  prep1_kernel<<<dim3(14336), dim3(256), 0, stream>>>(x, wq, wk, wv, xb, w1);
  // 2. fused QKV projection (N = 3072) with in-epilogue RoPE
  gemm_bf16<3><<<dim3(Md / 128, 3072 / 128), dim3(128), 0, stream>>>(xb, w1, Qb, Md, 3072, Cd);
  // 3. wo transpose into w1 (wqkvT dead after QKV GEMM)
  transpose_f2b<<<dim3(Cd / 32, Cd / 32), dim3(256), 0, stream>>>(wo, w1, Cd, Cd);
  // 4. attention -> yb (bf16 [M][C]); 8-wave LDS-staged blocks, LPT order
  attn_kernel<<<dim3(Bd * NH, 8), dim3(512), 0, stream>>>(Qb, Kb, Vtb, yb);
  // 5. output projection -> d_out (fp32)
  gemm_bf16<2><<<dim3(Md / 128, Cd / 128), dim3(128), 0, stream>>>(yb, w1, d_out, Md, Cd, Cd);
}

// Round 10
// 198.081 us; speedup vs baseline: 1.1495x; 1.1495x over previous
//
#include <hip/hip_runtime.h>
#include <hip/hip_bf16.h>
#include <cstdint>
#include <cstddef>

// ---------------------------------------------------------------------------
// LlamaAttention forward: out = Attn(RoPE(x@wq), RoPE(x@wk), x@wv) @ wo
// B=2 T=2048 C=2048 NH=32 NKV=8 D=64, causal, GQA rep=4, scale=1/8.
// R10: GEMM = R8 geometry (128^2, 4 waves, 64x64/wave, BK=64 dbuf) +
// T4 counted vmcnt: STAGE(t+1); vmcnt(8); s_barrier; compute(t);
// lgkmcnt(0); s_barrier. Next-tile loads stay in flight across the whole
// compute phase (R8's __syncthreads drained vmcnt to 0 every tile = the
// ~1400cy/tile stall). T5 setprio around MFMA cluster. R9's 2-wave tile
// reverted (1 wave/SIMD killed it).
// ---------------------------------------------------------------------------

using bf16 = __hip_bfloat16;
using f32x4  = __attribute__((ext_vector_type(4))) float;
using f32x16 = __attribute__((ext_vector_type(16))) float;
using short8 = __attribute__((ext_vector_type(8))) short;
using u32x4  = __attribute__((ext_vector_type(4))) unsigned int;

typedef __attribute__((address_space(1))) const void* gp1_t;
typedef __attribute__((address_space(3))) void*       lp3_t;

#define GLOAD_LDS16(g, l)                                                     \
  __builtin_amdgcn_global_load_lds((gp1_t)(const void*)(g), (lp3_t)(void*)(l), 16, 0, 0)

#define MFMA32(a, b, c) __builtin_amdgcn_mfma_f32_32x32x16_bf16(a, b, c, 0, 0, 0)

static constexpr int Bd  = 2;
static constexpr int Td  = 2048;
static constexpr int Cd  = 2048;
static constexpr int NH  = 32;
static constexpr int NKV = 8;
static constexpr int HD  = 64;
static constexpr int Md  = Bd * Td;     // 4096 rows

__device__ inline float bf2f(unsigned short u) {
  union { unsigned int i; float f; } v; v.i = ((unsigned int)u) << 16; return v.f;
}
__device__ inline unsigned short f2bfbits(float f) {
  union { float f; unsigned int u; } v; v.f = f;
  unsigned int r = v.u + 0x7fffu + ((v.u >> 16) & 1u);   // RNE
  return (unsigned short)(r >> 16);
}
__device__ inline unsigned int pkbf(float a, float b) {   // lo=bf16(a), hi=bf16(b)
  unsigned int r;
  asm("v_cvt_pk_bf16_f32 %0, %1, %2" : "=v"(r) : "v"(a), "v"(b));
  return r;
}
// v_permlane32_swap_b32 d, s:  after: d = {d.lo, s.lo}, s = {d.hi, s.hi}.
__device__ inline void plswapf(float& a, float& b) {
  asm("v_permlane32_swap_b32 %0, %1" : "+v"(a), "+v"(b));
}
__device__ inline void plswapu(unsigned int& a, unsigned int& b) {
  asm("v_permlane32_swap_b32 %0, %1" : "+v"(a), "+v"(b));
}
__device__ inline float hmax16(const f32x16& v) {
  float a0 = fmaxf(v[0], v[1]),   a1 = fmaxf(v[2], v[3]);
  float a2 = fmaxf(v[4], v[5]),   a3 = fmaxf(v[6], v[7]);
  float a4 = fmaxf(v[8], v[9]),   a5 = fmaxf(v[10], v[11]);
  float a6 = fmaxf(v[12], v[13]), a7 = fmaxf(v[14], v[15]);
  float b0 = fmaxf(a0, a1), b1 = fmaxf(a2, a3);
  float b2 = fmaxf(a4, a5), b3 = fmaxf(a6, a7);
  return fmaxf(fmaxf(b0, b1), fmaxf(b2, b3));
}
__device__ inline float hsum16(const f32x16& v) {
  float a0 = v[0]+v[1],   a1 = v[2]+v[3],   a2 = v[4]+v[5],   a3 = v[6]+v[7];
  float a4 = v[8]+v[9],   a5 = v[10]+v[11], a6 = v[12]+v[13], a7 = v[14]+v[15];
  float b0 = a0+a1, b1 = a2+a3, b2 = a4+a5, b3 = a6+a7;
  return (b0+b1)+(b2+b3);
}

// ---------------- prep1: x->bf16 + wq/wk/wv fp32->bf16^T -------------------
__global__ __launch_bounds__(256) void prep1_kernel(const float* __restrict__ x,
                                                    const float* __restrict__ wq,
                                                    const float* __restrict__ wk,
                                                    const float* __restrict__ wv,
                                                    bf16* __restrict__ xb,
                                                    bf16* __restrict__ w1) {
  __shared__ float tile[32][33];
  int bid = blockIdx.x, tid = threadIdx.x;
  if (bid < 8192) {
    int i = bid * 256 + tid;
    float4 v = ((const float4*)x)[i];
    ushort4 o;
    o.x = f2bfbits(v.x); o.y = f2bfbits(v.y); o.z = f2bfbits(v.z); o.w = f2bfbits(v.w);
    ((ushort4*)xb)[i] = o;
    return;
  }
  const float* in; bf16* out; int Cc, bx, by;
  if (bid < 12288)      { int l = bid - 8192;  in = wq; out = w1;                        Cc = 2048; bx = l & 63; by = l >> 6; }
  else if (bid < 13312) { int l = bid - 12288; in = wk; out = w1 + (size_t)2048 * 2048;  Cc = 512;  bx = l & 15; by = l >> 4; }
  else                  { int l = bid - 13312; in = wv; out = w1 + (size_t)2560 * 2048;  Cc = 512;  bx = l & 15; by = l >> 4; }
  int tx = tid & 31, ty = tid >> 5;
  int col = bx * 32 + tx;
#pragma unroll
  for (int i = 0; i < 4; ++i) {
    int row = by * 32 + ty + i * 8;
    tile[ty + i * 8][tx] = in[(size_t)row * Cc + col];
  }
  __syncthreads();
#pragma unroll
  for (int i = 0; i < 4; ++i) {
    int orow = bx * 32 + ty + i * 8;
    int ocol = by * 32 + tx;
    out[(size_t)orow * 2048 + ocol] = __float2bfloat16(tile[tx][ty + i * 8]);
  }
}

// ---------------- fp32 [R][Cc] -> bf16 transpose [Cc][R] (wo) --------------
__global__ __launch_bounds__(256) void transpose_f2b(const float* __restrict__ in,
                                                     bf16* __restrict__ out,
                                                     int R, int Cc) {
  __shared__ float tile[32][33];
  int tx = threadIdx.x & 31, ty = threadIdx.x >> 5;
  int bx = blockIdx.x, by = blockIdx.y;
  int col = bx * 32 + tx;
#pragma unroll
  for (int i = 0; i < 4; ++i) {
    int row = by * 32 + ty + i * 8;
    tile[ty + i * 8][tx] = in[(size_t)row * Cc + col];
  }
  __syncthreads();
#pragma unroll
  for (int i = 0; i < 4; ++i) {
    int orow = bx * 32 + ty + i * 8;
    int ocol = by * 32 + tx;
    out[(size_t)orow * R + ocol] = __float2bfloat16(tile[tx][ty + i * 8]);
  }
}

// ---------------- GEMM: C[M][N] = A[M][K] * Bt[N][K]^T ---------------------
// 128x128 tile, BK=64, 4 waves (2x2), 4x4 16x16 frags per wave.
// 2-phase double buffer with COUNTED vmcnt (T4): STAGE(t+1) -> vmcnt(8)
// (waits only tile t's 8 per-wave loads; t+1's stay in flight across the
// barrier + compute) -> s_barrier -> compute -> lgkmcnt(0) -> s_barrier.
// Both-sides XOR swizzle (conflict-free ds_read_b128). Natural 2D grid.
// MODE 2: fp32 row-major [M][N].
// MODE 3: fused QKV epilogue — in-register RoPE for Q (prescaled) and K;
//         V^T via wave-private LDS transpose.
template <int MODE>
__global__ __launch_bounds__(256, 2) void gemm_bf16(const bf16* __restrict__ A,
                                                    const bf16* __restrict__ Bt,
                                                    void* __restrict__ Cp,
                                                    int M, int N, int K) {
  __shared__ __align__(16) bf16 Al[2][128 * 64];   // 2 x 16 KB
  __shared__ __align__(16) bf16 Bl[2][128 * 64];   // 2 x 16 KB
  int tid = threadIdx.x;
  int w = tid >> 6, lane = tid & 63;
  int lr = lane & 15, lg = lane >> 4;
  int m0 = blockIdx.x * 128, n0 = blockIdx.y * 128;
  int wr = w >> 1, wc = w & 1;
  f32x4 acc[4][4] = {};

  size_t Kb = (size_t)K * 2;
  int c8 = lane & 7, r8 = lane >> 3;           // src chunk, row-in-octet
  const char* Asrc = (const char*)A + (size_t)(m0 + w * 8 + r8) * Kb + ((c8 ^ r8) << 4);
  const char* Bsrc = (const char*)Bt + (size_t)(n0 + w * 8 + r8) * Kb + ((c8 ^ r8) << 4);

#define GSTAGE(kt, bb) do {                                                   \
    char* ald = (char*)&Al[bb][0] + w * 1024;                                 \
    char* bld = (char*)&Bl[bb][0] + w * 1024;                                 \
    _Pragma("unroll")                                                         \
    for (int j = 0; j < 4; ++j) {                                             \
      GLOAD_LDS16(Asrc + (size_t)j * 32 * Kb + (size_t)(kt) * 2, ald + j * 4096); \
      GLOAD_LDS16(Bsrc + (size_t)j * 32 * Kb + (size_t)(kt) * 2, bld + j * 4096); \
    }                                                                         \
  } while (0)

  int nkt = K >> 6;
  GSTAGE(0, 0);
  asm volatile("s_waitcnt vmcnt(0)" ::: "memory");
  __builtin_amdgcn_s_barrier();
  __builtin_amdgcn_sched_barrier(0);

  for (int t = 0; t < nkt; ++t) {
    int cur = t & 1;
    if (t + 1 < nkt) {
      GSTAGE((t + 1) << 6, cur ^ 1);   // issue next-tile loads (stay in flight)
      asm volatile("s_waitcnt vmcnt(8)" ::: "memory");   // wait tile t only
    } else {
      asm volatile("s_waitcnt vmcnt(0)" ::: "memory");
    }
    __builtin_amdgcn_s_barrier();      // all waves' tile-t DMAs landed
    __builtin_amdgcn_sched_barrier(0);
    const char* Ab = (const char*)&Al[cur][0];
    const char* Bb = (const char*)&Bl[cur][0];
    __builtin_amdgcn_s_setprio(1);
#pragma unroll
    for (int kk = 0; kk < 2; ++kk) {
      short8 af[4], bfr[4];
#pragma unroll
      for (int f = 0; f < 4; ++f) {
        int ra = wr * 64 + f * 16 + lr;
        int rb = wc * 64 + f * 16 + lr;
        int cb = (((kk << 2) | lg) ^ (lr & 7)) << 4;
        af[f]  = *(const short8*)(Ab + (size_t)ra * 128 + cb);
        bfr[f] = *(const short8*)(Bb + (size_t)rb * 128 + cb);
      }
#pragma unroll
      for (int i = 0; i < 4; ++i)
#pragma unroll
        for (int j = 0; j < 4; ++j)
          acc[i][j] = __builtin_amdgcn_mfma_f32_16x16x32_bf16(af[i], bfr[j], acc[i][j], 0, 0, 0);
    }
    __builtin_amdgcn_s_setprio(0);
    asm volatile("s_waitcnt lgkmcnt(0)" ::: "memory");   // ds_reads of buf done
    __builtin_amdgcn_sched_barrier(0);
    __builtin_amdgcn_s_barrier();      // before t+2 DMA overwrites this buf
  }
#undef GSTAGE

  bf16* Qb  = (bf16*)Cp;
  bf16* Kb2 = Qb + (size_t)Bd * NH * Td * HD;
  bf16* Vtb = Kb2 + (size_t)Bd * NKV * Td * HD;

  if (MODE == 3 && n0 >= 2560) {
    // ---- V^T epilogue: wave-private LDS transpose, coalesced stores ----
    int h  = (n0 - 2560 + wc * 64) >> 6;
    int b  = m0 >> 11;
    int tg = (m0 & 2047) + wr * 64;
    char* tb = (w < 2 ? (char*)&Al[0][0] : (char*)&Bl[0][0]) + (w & 1) * 8192;
#pragma unroll
    for (int i = 0; i < 4; ++i)
#pragma unroll
      for (int j = 0; j < 4; ++j)
#pragma unroll
        for (int r = 0; r < 4; r += 2) {
          int d  = j * 16 + lr;
          int tt = i * 16 + lg * 4 + r;
          unsigned int pk = pkbf(acc[i][j][r], acc[i][j][r + 1]);
          *(unsigned int*)(tb + (((size_t)d * 128 + tt * 2) ^ ((d & 7) << 4))) = pk;
        }
    asm volatile("s_waitcnt lgkmcnt(0)" ::: "memory");
    __builtin_amdgcn_sched_barrier(0);
    char* Vdst = (char*)Vtb + ((((size_t)b * NKV + h) * 64) * Td + tg) * 2;
#pragma unroll
    for (int p = 0; p < 8; ++p) {
      int d  = p * 8 + (lane >> 3);
      int tc = lane & 7;
      u32x4 v = *(const u32x4*)(tb + (((size_t)d * 128 + tc * 16) ^ ((d & 7) << 4)));
      *(u32x4*)(Vdst + (size_t)d * Td * 2 + tc * 16) = v;
    }
    return;
  }

  if (MODE == 3) {
    // ---- Q/K epilogue with fused RoPE ----
    const float RC = -0.41524101186092029f;        // -log2(10000)/32
    float sc = (n0 < 2048) ? 0.18033688011112042f : 1.0f;   // Q: 0.125*log2e
    int odd = lane & 1;
#pragma unroll
    for (int j = 0; j < 4; ++j) {
      int ncol = n0 + wc * 64 + j * 16 + lr;
      int d  = ncol & 63;
      float inv = __builtin_amdgcn_exp2f((float)(d >> 1) * RC);
#pragma unroll
      for (int i = 0; i < 4; ++i) {
#pragma unroll
        for (int r = 0; r < 4; ++r) {
          int mrow = m0 + wr * 64 + i * 16 + lg * 4 + r;
          int t = mrow & 2047;
          float v = acc[i][j][r];
          float p = __shfl_xor(v, 1);
          float rev = (float)t * inv * 0.15915494309189535f;
          rev = rev - floorf(rev);
          float s = __builtin_amdgcn_sinf(rev);
          float c = __builtin_amdgcn_cosf(rev);
          float res = odd ? (v * c + p * s) : (v * c - p * s);
          res *= sc;
          int b = mrow >> 11;
          if (n0 < 2048) {
            int h = ncol >> 6;
            Qb[(((size_t)b * NH + h) * Td + t) * HD + d] = __float2bfloat16(res);
          } else {
            int h = (ncol - 2048) >> 6;
            Kb2[(((size_t)b * NKV + h) * Td + t) * HD + d] = __float2bfloat16(res);
          }
        }
      }
    }
    return;
  }

#pragma unroll
  for (int i = 0; i < 4; ++i)
#pragma unroll
    for (int j = 0; j < 4; ++j)
#pragma unroll
      for (int r = 0; r < 4; ++r) {
        int mrow = m0 + wr * 64 + i * 16 + lg * 4 + r;
        int ncol = n0 + wc * 64 + j * 16 + lr;
        ((float*)Cp)[(size_t)mrow * N + ncol] = acc[i][j][r];
      }
}

// ---------------- Flash attention (causal, GQA), LDS-staged KV -------------
// grid (B*NH=64, 8 qb), 512 thr = 8 waves; wave w owns q rows qb*256+w*32..+31.
// LPT: qb = 7 - blockIdx.y (heavy blocks first).
// Per kv tile (64x64): wave w stages K rows [w*8,w*8+8) and Vt rows [w*8,+8)
// via ONE global_load_lds dwordx4 each (coalesced), inverse-XOR-swizzled src.
// 2-phase double buffer: STAGE(next) -> compute(cur) -> vmcnt(0)+barrier.
// Softmax: swapped QK^T (S^T col=q=lane&31), in-register, T12 pack, T13 defer.
__global__ __launch_bounds__(512, 4) void attn_kernel(const bf16* __restrict__ Q,
                                                      const bf16* __restrict__ K,
                                                      const bf16* __restrict__ Vt,
                                                      bf16* __restrict__ Y) {
  __shared__ __align__(16) char lds[2 * 16384];   // [buf][K 8KB | V 8KB]
  int tid = threadIdx.x, w = tid >> 6, lane = tid & 63;
  int lq = lane & 31;          // q column (and kv/d row within subtile)
  int H  = lane >> 5;          // lane half
  int qb = 7 - (int)blockIdx.y;
  int bh = blockIdx.x;
  int b = bh >> 5, h = bh & 31, kvh = h >> 2;
  int q0w = qb * 256 + w * 32;
  int qg  = q0w + lq;
  int tmax = qb * 4 + (w >> 1);    // this wave's last compute tile
  int Nt   = qb * 4 + 4;           // tiles staged by the block

  const bf16* Qp = Q + (((size_t)b * NH + h) * Td) * HD;
  const char* Kg = (const char*)(K + (((size_t)b * NKV + kvh) * Td) * HD);   // rows 128B
  const char* Vg = (const char*)(Vt + (((size_t)b * NKV + kvh) * HD) * Td);  // rows 4096B

  // Q B-fragments (pre-scaled in QKV epilogue): qf[ck][j] = Q[qg][ck*16+H*8+j]
  short8 qf[4];
#pragma unroll
  for (int ck = 0; ck < 4; ++ck)
    qf[ck] = *(const short8*)(Qp + (size_t)qg * HD + ck * 16 + H * 8);

  // staging geometry: wave w stages tile rows [w*8, w*8+8), 16B per lane
  int srow   = lane >> 3;                       // 0..7 within the 8-row slab
  int scol16 = ((lane & 7) ^ srow) << 4;        // inverse-swizzled byte col
  const char* Ksrc0 = Kg + (size_t)(w * 8 + srow) * 128 + scol16;
  const char* Vsrc0 = Vg + (size_t)(w * 8 + srow) * 4096 + scol16;
  char* KldsW[2] = { lds + w * 1024,          lds + 16384 + w * 1024 };
  char* VldsW[2] = { lds + 8192 + w * 1024,   lds + 24576 + w * 1024 };

#define STAGE_KV(tt, bb) do {                                                 \
    GLOAD_LDS16(Ksrc0 + (size_t)(tt) * 64 * 128, KldsW[bb]);                  \
    GLOAD_LDS16(Vsrc0 + (size_t)(tt) * 128,      VldsW[bb]);                  \
  } while (0)

  f32x16 acc0 = {}, acc1 = {};     // O^T[d][q], d 0..31 / 32..63
  float m = -3e38f, l = 0.0f;
  int swz = (lq & 7) << 4;
  int rb0 = lq * 128, rb1 = (32 + lq) * 128;

  STAGE_KV(0, 0);
  asm volatile("s_waitcnt vmcnt(0)" ::: "memory");
  __syncthreads();

  for (int t = 0; t < Nt; ++t) {
    int cur = t & 1;
    if (t + 1 < Nt) STAGE_KV(t + 1, cur ^ 1);
    if (t <= tmax) {
      const char* Kl = lds + cur * 16384;
      const char* Vl = Kl + 8192;
      // ---- S^T = K . Q^T ----
      f32x16 s0 = {}, s1 = {};
      __builtin_amdgcn_s_setprio(1);
#pragma unroll
      for (int ck = 0; ck < 4; ++ck) {
        int c = (H * 16 + ck * 32) ^ swz;
        short8 kf0 = *(const short8*)(Kl + rb0 + c);
        short8 kf1 = *(const short8*)(Kl + rb1 + c);
        s0 = MFMA32(kf0, qf[ck], s0);
        s1 = MFMA32(kf1, qf[ck], s1);
      }
      __builtin_amdgcn_s_setprio(0);
      // ---- causal mask (diagonal tile only) ----
      if (t == tmax) {
        int kvb = t * 64;
#pragma unroll
        for (int rr = 0; rr < 16; ++rr) {
          int krel = (rr & 3) + 8 * (rr >> 2) + 4 * H;
          if (kvb + krel > qg)      s0[rr] = -3e38f;
          if (kvb + 32 + krel > qg) s1[rr] = -3e38f;
        }
      }
      // ---- row max (register tree + cross-half permlane swap) ----
      float mx = fmaxf(hmax16(s0), hmax16(s1));
      {
        float mb = mx;
        asm("" : "+v"(mb));
        plswapf(mx, mb);
        mx = fmaxf(mx, mb);
      }
      // ---- defer-rescale (T13, THR=8 in log2 domain) ----
      if (__any(mx > m + 8.0f)) {
        float mn = fmaxf(m, mx);
        float al = __builtin_amdgcn_exp2f(m - mn);
        m = mn;
        l *= al;
#pragma unroll
        for (int rr = 0; rr < 16; ++rr) { acc0[rr] *= al; acc1[rr] *= al; }
      }
      // ---- p = exp2(s - m) ----
#pragma unroll
      for (int rr = 0; rr < 16; ++rr) {
        s0[rr] = __builtin_amdgcn_exp2f(s0[rr] - m);
        s1[rr] = __builtin_amdgcn_exp2f(s1[rr] - m);
      }
      float ps = hsum16(s0) + hsum16(s1);
      {
        float pb = ps;
        asm("" : "+v"(pb));
        plswapf(ps, pb);
        ps += pb;
      }
      l += ps;
      // ---- pack P -> bf16 B-fragments (T12: cvt_pk + permlane32_swap) ----
      short8 pf[4];
#pragma unroll
      for (int tt = 0; tt < 2; ++tt) {
        const f32x16& sv = tt ? s1 : s0;
#pragma unroll
        for (int a2 = 0; a2 < 2; ++a2) {
          unsigned int A0 = pkbf(sv[8*a2 + 0], sv[8*a2 + 1]);
          unsigned int A1 = pkbf(sv[8*a2 + 2], sv[8*a2 + 3]);
          unsigned int B0 = pkbf(sv[8*a2 + 4], sv[8*a2 + 5]);
          unsigned int B1 = pkbf(sv[8*a2 + 6], sv[8*a2 + 7]);
          plswapu(A0, B0);
          plswapu(A1, B1);
          u32x4 t4;
          t4[0] = A0; t4[1] = A1; t4[2] = B0; t4[3] = B1;
          pf[2*tt + a2] = __builtin_bit_cast(short8, t4);
        }
      }
      // ---- O^T += V^T . P ----
      __builtin_amdgcn_s_setprio(1);
#pragma unroll
      for (int ks = 0; ks < 4; ++ks) {
        int c = (H * 16 + ks * 32) ^ swz;
        short8 vf0 = *(const short8*)(Vl + rb0 + c);
        short8 vf1 = *(const short8*)(Vl + rb1 + c);
        acc0 = MFMA32(vf0, pf[ks], acc0);
        acc1 = MFMA32(vf1, pf[ks], acc1);
      }
      __builtin_amdgcn_s_setprio(0);
    }
    asm volatile("s_waitcnt vmcnt(0)" ::: "memory");
    __syncthreads();
  }
#undef STAGE_KV

  // ---- epilogue: normalize, write Y[M][C] ----
  float rn = 1.0f / l;
  bf16* Yp = Y + ((size_t)b * Td + qg) * Cd + h * HD;
#pragma unroll
  for (int rr = 0; rr < 16; rr += 2) {
    int d = (rr & 3) + 8 * (rr >> 2) + 4 * H;   // d, d+1 for rr, rr+1
    unsigned int w0 = pkbf(acc0[rr] * rn, acc0[rr + 1] * rn);
    unsigned int w1 = pkbf(acc1[rr] * rn, acc1[rr + 1] * rn);
    *(unsigned int*)(Yp + d)      = w0;
    *(unsigned int*)(Yp + 32 + d) = w1;
  }
}

// ---------------------------------------------------------------------------
extern "C" void kernel_launch(void* const* d_in, const int* in_sizes, int n_in,
                              void* d_out, int out_size, void* d_ws, size_t ws_size,
                              hipStream_t stream) {
  const float* x  = (const float*)d_in[0];
  const float* wq = (const float*)d_in[1];
  const float* wk = (const float*)d_in[2];
  const float* wv = (const float*)d_in[3];
  const float* wo = (const float*)d_in[4];

  char* ws = (char*)d_ws;
  const size_t o_xb = 0;                                   // 16.78 MB (reused as yb)
  const size_t o_w1 = o_xb + (size_t)Md * Cd * 2;          // 12.58 MB (wqkvT / later woT)
  const size_t o_Q  = o_w1 + (size_t)3072 * Cd * 2;        // 16.78 MB
  const size_t o_K  = o_Q + (size_t)Bd * NH * Td * HD * 2; // 4.19 MB
  const size_t o_V  = o_K + (size_t)Bd * NKV * Td * HD * 2;// 4.19 MB

  bf16* xb  = (bf16*)(ws + o_xb);
  bf16* w1  = (bf16*)(ws + o_w1);
  bf16* Qb  = (bf16*)(ws + o_Q);
  bf16* Kb  = (bf16*)(ws + o_K);
  bf16* Vtb = (bf16*)(ws + o_V);
  bf16* yb  = xb;   // alias: x_bf16 dead after QKV GEMM

  // 1. prep1: x->bf16 + wq/wk/wv transposes (one launch)
  prep1_kernel<<<dim3(14336), dim3(256), 0, stream>>>(x, wq, wk, wv, xb, w1);
  // 2. fused QKV projection (N = 3072) with in-epilogue RoPE
  gemm_bf16<3><<<dim3(Md / 128, 3072 / 128), dim3(256), 0, stream>>>(xb, w1, Qb, Md, 3072, Cd);
  // 3. wo transpose into w1 (wqkvT dead after QKV GEMM)
  transpose_f2b<<<dim3(Cd / 32, Cd / 32), dim3(256), 0, stream>>>(wo, w1, Cd, Cd);
  // 4. attention -> yb (bf16 [M][C]); 8-wave LDS-staged blocks, LPT order
  attn_kernel<<<dim3(Bd * NH, 8), dim3(512), 0, stream>>>(Qb, Kb, Vtb, yb);
  // 5. output projection -> d_out (fp32)
  gemm_bf16<2><<<dim3(Md / 128, Cd / 128), dim3(256), 0, stream>>>(yb, w1, d_out, Md, Cd, Cd);
}